// Round 4
// baseline (247.089 us; speedup 1.0000x reference)
//
#include <hip/hip_runtime.h>
#include <hip/hip_bf16.h>
#include <math.h>

#define SSEG 640
#define PPP_ 250
#define NF 147

// ---------------------------------------------------------------------------
// kA: blocks 0..639    geometry: per-segment mean + quat rotate -> rm(640,3),
//                      nerf embed -> nb(640,147)
//     blocks 640..671  temb MLP both layers for batch b=blk-640 -> temb2(32,512)
//                      (float4 weight loads, 2-way k-split, LDS reduce)
//     block  672       zero stats[768] + 2 barrier counters
// ---------------------------------------------------------------------------
__global__ __launch_bounds__(256) void kA(
    const float* __restrict__ noise, const float* __restrict__ pcs,
    const int* __restrict__ bl, const int* __restrict__ tsteps,
    const float* __restrict__ t_w1, const float* __restrict__ t_b1,
    const float* __restrict__ t_w2, const float* __restrict__ t_b2,
    float* __restrict__ rm, float* __restrict__ nb,
    float* __restrict__ temb2, int* __restrict__ statsz)
{
    int blk = blockIdx.x, tid = threadIdx.x;

    if (blk < SSEG) {
        int s = blk;
        float sx = 0.f, sy = 0.f, sz = 0.f;
        if (tid < PPP_) {
            const float* p = pcs + (size_t)(s * PPP_ + tid) * 3;
            sx = p[0]; sy = p[1]; sz = p[2];
        }
        for (int off = 32; off >= 1; off >>= 1) {
            sx += __shfl_down(sx, off, 64);
            sy += __shfl_down(sy, off, 64);
            sz += __shfl_down(sz, off, 64);
        }
        __shared__ float wsum[4][3];
        __shared__ float np7[7];
        int wave = tid >> 6, lane = tid & 63;
        if (lane == 0) { wsum[wave][0] = sx; wsum[wave][1] = sy; wsum[wave][2] = sz; }
        if (tid < 7) np7[tid] = noise[s * 7 + tid];
        __syncthreads();
        if (tid == 0) {
            float inv = 1.f / (float)bl[s];
            float mx = (wsum[0][0] + wsum[1][0] + wsum[2][0] + wsum[3][0]) * inv;
            float my = (wsum[0][1] + wsum[1][1] + wsum[2][1] + wsum[3][1]) * inv;
            float mz = (wsum[0][2] + wsum[1][2] + wsum[2][2] + wsum[3][2]) * inv;
            float qw = np7[3], qx = np7[4], qy = np7[5], qz = np7[6];
            float qn = rsqrtf(qw * qw + qx * qx + qy * qy + qz * qz);
            qw *= qn; qx *= qn; qy *= qn; qz *= qn;
            float tx = 2.f * (qy * mz - qz * my);
            float ty = 2.f * (qz * mx - qx * mz);
            float tz = 2.f * (qx * my - qy * mx);
            rm[s * 3 + 0] = mx + qw * tx + (qy * tz - qz * ty) + np7[0];
            rm[s * 3 + 1] = my + qw * ty + (qz * tx - qx * tz) + np7[1];
            rm[s * 3 + 2] = mz + qw * tz + (qx * ty - qy * tx) + np7[2];
        }
        if (tid < NF) {
            float v;
            if (tid < 7) v = np7[tid];
            else {
                int j = tid - 7;
                int fi = j / 14, r = j % 14;
                float band = (float)(1 << fi);
                v = (r < 7) ? sinf(np7[r] * band) : cosf(np7[r - 7] * band);
            }
            nb[s * NF + tid] = v;
        }
    } else if (blk < SSEG + 32) {
        int b = blk - SSEG;
        __shared__ float e[512];
        __shared__ float red[2][512];
        float tf = (float)tsteps[b];
        float f = expf(-9.210340371976184f * (float)tid * (1.f / 256.f));
        float a = tf * f;
        e[tid] = cosf(a);
        e[tid + 256] = sinf(a);
        __syncthreads();

        int jq = (tid & 127) << 2;   // j0 in {0,4,...,508}
        int ks = tid >> 7;           // k-split 0/1
        int k0 = ks << 8;

        // ---- layer 1 ----
        float4 acc = {0.f, 0.f, 0.f, 0.f};
        #pragma unroll 8
        for (int k = k0; k < k0 + 256; k++) {
            float4 w = *(const float4*)&t_w1[k * 512 + jq];
            float s = e[k];
            acc.x += s * w.x; acc.y += s * w.y; acc.z += s * w.z; acc.w += s * w.w;
        }
        *(float4*)&red[ks][jq] = acc;
        __syncthreads();
        #pragma unroll 2
        for (int j = tid; j < 512; j += 256) {
            float v = red[0][j] + red[1][j] + t_b1[j];
            float sig = 1.f / (1.f + expf(-v));
            e[j] = v * sig;          // h1 reuses e
        }
        __syncthreads();

        // ---- layer 2 ----
        acc.x = 0.f; acc.y = 0.f; acc.z = 0.f; acc.w = 0.f;
        #pragma unroll 8
        for (int k = k0; k < k0 + 256; k++) {
            float4 w = *(const float4*)&t_w2[k * 512 + jq];
            float s = e[k];
            acc.x += s * w.x; acc.y += s * w.y; acc.z += s * w.z; acc.w += s * w.w;
        }
        *(float4*)&red[ks][jq] = acc;
        __syncthreads();
        #pragma unroll 2
        for (int j = tid; j < 512; j += 256)
            temb2[b * 512 + j] = red[0][j] + red[1][j] + t_b2[j];
    } else {
        for (int z = tid; z < 772; z += 256) statsz[z] = 0;
    }
}

// ---------------------------------------------------------------------------
// kB: blocks 0..159   4 segments each: pool-base (no temb2) in LDS, then
//                     fc1 via double-buffered LDS-staged o_w1 tiles ->
//                     g1[s][c] (no bias, no temb contribution)
//     blocks 160..191 tG[b][c] = temb2[b]·o_w1[:,c] + o_b1[c]
// ---------------------------------------------------------------------------
__global__ __launch_bounds__(256) void kB(
    const float* __restrict__ rm, const float* __restrict__ nb,
    const float* __restrict__ temb2,
    const float* __restrict__ pe_w, const float* __restrict__ pe_b,
    const float* __restrict__ pfc_w, const float* __restrict__ pfc_b,
    const float* __restrict__ o_w1, const float* __restrict__ o_b1,
    float* __restrict__ g1, float* __restrict__ tg)
{
    int blk = blockIdx.x, tid = threadIdx.x;
    __shared__ float pool[4][512];
    __shared__ float wt[2][16][256];

    if (blk < 160) {
        int s0 = blk * 4;
        __shared__ float nbs[4][NF + 1];
        __shared__ float rms[4][3];
        for (int i = tid; i < 4 * NF; i += 256) nbs[i / NF][i % NF] = nb[s0 * NF + i];
        if (tid < 12) rms[tid / 3][tid % 3] = rm[s0 * 3 + tid];
        __syncthreads();
        #pragma unroll
        for (int h = 0; h < 2; h++) {
            int j = h * 256 + tid;
            float base = pfc_b[j] + pe_b[j];
            float w0 = pe_w[j], w1 = pe_w[512 + j], w2 = pe_w[1024 + j];
            float a0 = base + rms[0][0] * w0 + rms[0][1] * w1 + rms[0][2] * w2;
            float a1 = base + rms[1][0] * w0 + rms[1][1] * w1 + rms[1][2] * w2;
            float a2 = base + rms[2][0] * w0 + rms[2][1] * w1 + rms[2][2] * w2;
            float a3 = base + rms[3][0] * w0 + rms[3][1] * w1 + rms[3][2] * w2;
            #pragma unroll 7
            for (int k = 0; k < NF; k++) {
                float w = pfc_w[k * 512 + j];
                a0 += nbs[0][k] * w; a1 += nbs[1][k] * w;
                a2 += nbs[2][k] * w; a3 += nbs[3][k] * w;
            }
            pool[0][j] = a0; pool[1][j] = a1; pool[2][j] = a2; pool[3][j] = a3;
        }
        __syncthreads();
        float acc0 = 0.f, acc1 = 0.f, acc2 = 0.f, acc3 = 0.f;
        for (int t = 0; t < 32; t++) {
            int buf = t & 1, k0 = t * 16;
            #pragma unroll 4
            for (int q = 0; q < 4; q++) {
                int idx = q * 256 + tid;            // 0..1023
                int row = idx >> 6, c4 = (idx & 63) << 2;
                *(float4*)&wt[buf][row][c4] = *(const float4*)&o_w1[(k0 + row) * 256 + c4];
            }
            __syncthreads();
            #pragma unroll 16
            for (int i = 0; i < 16; i++) {
                float w = wt[buf][i][tid];
                acc0 += pool[0][k0 + i] * w;
                acc1 += pool[1][k0 + i] * w;
                acc2 += pool[2][k0 + i] * w;
                acc3 += pool[3][k0 + i] * w;
            }
        }
        g1[(s0 + 0) * 256 + tid] = acc0;
        g1[(s0 + 1) * 256 + tid] = acc1;
        g1[(s0 + 2) * 256 + tid] = acc2;
        g1[(s0 + 3) * 256 + tid] = acc3;
    } else {
        int b = blk - 160;
        for (int i = tid; i < 512; i += 256) pool[0][i] = temb2[b * 512 + i];
        __syncthreads();
        float acc = o_b1[tid];
        for (int t = 0; t < 32; t++) {
            int buf = t & 1, k0 = t * 16;
            #pragma unroll 4
            for (int q = 0; q < 4; q++) {
                int idx = q * 256 + tid;
                int row = idx >> 6, c4 = (idx & 63) << 2;
                *(float4*)&wt[buf][row][c4] = *(const float4*)&o_w1[(k0 + row) * 256 + c4];
            }
            __syncthreads();
            #pragma unroll 16
            for (int i = 0; i < 16; i++) acc += pool[0][k0 + i] * wt[buf][i][tid];
        }
        tg[b * 256 + tid] = acc;
    }
}

// ---------------------------------------------------------------------------
// kCD: 80 blocks x 128 threads, co-resident (<=1 block/CU needed: 80 < 256).
//   phase0: rows = g1 + tG (full fc1 output), local col sums -> stats1 atomics
//   barrier1 ; bn1+relu ; fc2 -> acc[8] ; stats2 atomics ; barrier2
//   bn2+relu ; fc3 -> out(640,7)
// ---------------------------------------------------------------------------
__global__ __launch_bounds__(128) void kCD(
    const float* __restrict__ g1, const float* __restrict__ tg,
    float* __restrict__ stats1,
    const float* __restrict__ bn1_g, const float* __restrict__ bn1_b,
    const float* __restrict__ o_w2, const float* __restrict__ o_b2,
    const float* __restrict__ bn2_g, const float* __restrict__ bn2_b,
    const float* __restrict__ o_w3, const float* __restrict__ o_b3,
    float* __restrict__ stats2, int* __restrict__ cntA, int* __restrict__ cntB,
    float* __restrict__ out)
{
    int blk = blockIdx.x, tid = threadIdx.x;
    int r0 = blk * 8;
    __shared__ float rows[8][256];
    __shared__ float scale[256], shift[256];
    __shared__ float rowsB[8][128];
    __shared__ float w3[128 * 7];

    for (int i = tid; i < 2048; i += 128) {
        int r = i >> 8, c = i & 255;
        int s = r0 + r;
        rows[r][c] = g1[s * 256 + c] + tg[(s / 20) * 256 + c];
    }
    for (int i = tid; i < 128 * 7; i += 128) w3[i] = o_w3[i];
    __syncthreads();
    for (int c = tid; c < 256; c += 128) {
        float sm = 0.f, ss = 0.f;
        #pragma unroll
        for (int r = 0; r < 8; r++) { float x = rows[r][c]; sm += x; ss += x * x; }
        atomicAdd(&stats1[c], sm);
        atomicAdd(&stats1[256 + c], ss);
    }

    __syncthreads();
    if (tid == 0) {
        __threadfence();
        atomicAdd(cntA, 1);
        while (atomicAdd(cntA, 0) < 80) { }
        __threadfence();
    }
    __syncthreads();

    for (int c = tid; c < 256; c += 128) {
        float m = stats1[c] * (1.f / 640.f);
        float v = stats1[256 + c] * (1.f / 640.f) - m * m;
        float sc = rsqrtf(v + 1e-5f) * bn1_g[c];
        scale[c] = sc;
        shift[c] = bn1_b[c] - m * sc;
    }
    __syncthreads();
    for (int i = tid; i < 2048; i += 128) {
        int r = i >> 8, c = i & 255;
        float x = rows[r][c] * scale[c] + shift[c];
        rows[r][c] = x > 0.f ? x : 0.f;
    }
    __syncthreads();

    float acc[8];
    float bb = o_b2[tid];
    #pragma unroll
    for (int r = 0; r < 8; r++) acc[r] = bb;
    #pragma unroll 8
    for (int k = 0; k < 256; k++) {
        float w = o_w2[k * 128 + tid];
        #pragma unroll
        for (int r = 0; r < 8; r++) acc[r] += rows[r][k] * w;
    }
    float sm = 0.f, ss = 0.f;
    #pragma unroll
    for (int r = 0; r < 8; r++) { sm += acc[r]; ss += acc[r] * acc[r]; }
    atomicAdd(&stats2[tid], sm);
    atomicAdd(&stats2[128 + tid], ss);

    __syncthreads();
    if (tid == 0) {
        __threadfence();
        atomicAdd(cntB, 1);
        while (atomicAdd(cntB, 0) < 80) { }
        __threadfence();
    }
    __syncthreads();

    {
        float m = stats2[tid] * (1.f / 640.f);
        float v = stats2[128 + tid] * (1.f / 640.f) - m * m;
        float sc = rsqrtf(v + 1e-5f) * bn2_g[tid];
        float sh = bn2_b[tid] - m * sc;
        #pragma unroll
        for (int r = 0; r < 8; r++) {
            float x = acc[r] * sc + sh;
            rowsB[r][tid] = x > 0.f ? x : 0.f;
        }
    }
    __syncthreads();
    if (tid < 56) {
        int r = tid / 7, j = tid % 7;
        float a3 = o_b3[j];
        #pragma unroll 8
        for (int k = 0; k < 128; k++) a3 += rowsB[r][k] * w3[k * 7 + j];
        out[(r0 + r) * 7 + j] = a3;
    }
}

extern "C" void kernel_launch(void* const* d_in, const int* in_sizes, int n_in,
                              void* d_out, int out_size, void* d_ws, size_t ws_size,
                              hipStream_t stream) {
    const float* noise = (const float*)d_in[0];
    const int* tsteps = (const int*)d_in[1];
    const float* pcs = (const float*)d_in[2];
    const int* bl = (const int*)d_in[4];
    const float* pe_w = (const float*)d_in[5];
    const float* pe_b = (const float*)d_in[6];
    const float* t_w1 = (const float*)d_in[7];
    const float* t_b1 = (const float*)d_in[8];
    const float* t_w2 = (const float*)d_in[9];
    const float* t_b2 = (const float*)d_in[10];
    const float* pfc_w = (const float*)d_in[11];
    const float* pfc_b = (const float*)d_in[12];
    const float* o_w1 = (const float*)d_in[13];
    const float* o_b1 = (const float*)d_in[14];
    const float* bn1_g = (const float*)d_in[15];
    const float* bn1_b = (const float*)d_in[16];
    const float* o_w2 = (const float*)d_in[17];
    const float* o_b2 = (const float*)d_in[18];
    const float* bn2_g = (const float*)d_in[19];
    const float* bn2_b = (const float*)d_in[20];
    const float* o_w3 = (const float*)d_in[21];
    const float* o_b3 = (const float*)d_in[22];

    float* ws = (float*)d_ws;
    float* rm    = ws + 0;        // 1920
    float* nb    = ws + 1920;     // 94080 -> 96000
    float* temb2 = ws + 96000;    // 16384 -> 112384
    float* g1    = ws + 112384;   // 163840 -> 276224
    float* tg    = ws + 276224;   // 8192  -> 284416
    float* stats = ws + 284416;   // 768 (stats1:512, stats2:256)
    int*   cnt   = (int*)(ws + 285184); // 2 counters (zeroed by kA with stats)

    kA<<<SSEG + 33, 256, 0, stream>>>(noise, pcs, bl, tsteps, t_w1, t_b1, t_w2, t_b2,
                                      rm, nb, temb2, (int*)stats);
    kB<<<192, 256, 0, stream>>>(rm, nb, temb2, pe_w, pe_b, pfc_w, pfc_b,
                                o_w1, o_b1, g1, tg);
    kCD<<<80, 128, 0, stream>>>(g1, tg, stats, bn1_g, bn1_b, o_w2, o_b2,
                                bn2_g, bn2_b, o_w3, o_b3,
                                stats + 512, cnt, cnt + 1, (float*)d_out);
}

// Round 5
// 192.972 us; speedup vs baseline: 1.2804x; 1.2804x over previous
//
#include <hip/hip_runtime.h>
#include <hip/hip_bf16.h>
#include <math.h>

#define SSEG 640
#define PPP_ 250
#define NF 147

// ---------------------------------------------------------------------------
// kA (899 blocks x 256):
//   0..639    geometry: segment mean + quat rotate -> rm(640,3); nerf -> nb(640,147)
//   640..767  temb layer1: h1 = silu(e @ t_w1 + t_b1)  (32 b x 4 j-quarters, k-split 2)
//   768..895  M = t_w2 @ o_w1  (512x256; 4 rows/block, float4 cols)
//   896..897  cv = t_b2 @ o_w1 + o_b1 (2 c-halves, k-split 2)
//   898       zero stats[768] + 2 barrier counters
// ---------------------------------------------------------------------------
__global__ __launch_bounds__(256) void kA(
    const float* __restrict__ noise, const float* __restrict__ pcs,
    const int* __restrict__ bl, const int* __restrict__ tsteps,
    const float* __restrict__ t_w1, const float* __restrict__ t_b1,
    const float* __restrict__ t_w2, const float* __restrict__ t_b2,
    const float* __restrict__ o_w1, const float* __restrict__ o_b1,
    float* __restrict__ rm, float* __restrict__ nb,
    float* __restrict__ h1, float* __restrict__ Mm, float* __restrict__ cv,
    int* __restrict__ statsz)
{
    __shared__ float sh[768];
    int blk = blockIdx.x, tid = threadIdx.x;

    if (blk < SSEG) {
        int s = blk;
        float sx = 0.f, sy = 0.f, sz = 0.f;
        if (tid < PPP_) {
            const float* p = pcs + (size_t)(s * PPP_ + tid) * 3;
            sx = p[0]; sy = p[1]; sz = p[2];
        }
        for (int off = 32; off >= 1; off >>= 1) {
            sx += __shfl_down(sx, off, 64);
            sy += __shfl_down(sy, off, 64);
            sz += __shfl_down(sz, off, 64);
        }
        float* wsum = sh;        // [4][3]
        float* np7 = sh + 12;    // [7]
        int wave = tid >> 6, lane = tid & 63;
        if (lane == 0) { wsum[wave * 3] = sx; wsum[wave * 3 + 1] = sy; wsum[wave * 3 + 2] = sz; }
        if (tid < 7) np7[tid] = noise[s * 7 + tid];
        __syncthreads();
        if (tid == 0) {
            float inv = 1.f / (float)bl[s];
            float mx = (wsum[0] + wsum[3] + wsum[6] + wsum[9]) * inv;
            float my = (wsum[1] + wsum[4] + wsum[7] + wsum[10]) * inv;
            float mz = (wsum[2] + wsum[5] + wsum[8] + wsum[11]) * inv;
            float qw = np7[3], qx = np7[4], qy = np7[5], qz = np7[6];
            float qn = rsqrtf(qw * qw + qx * qx + qy * qy + qz * qz);
            qw *= qn; qx *= qn; qy *= qn; qz *= qn;
            float tx = 2.f * (qy * mz - qz * my);
            float ty = 2.f * (qz * mx - qx * mz);
            float tz = 2.f * (qx * my - qy * mx);
            rm[s * 3 + 0] = mx + qw * tx + (qy * tz - qz * ty) + np7[0];
            rm[s * 3 + 1] = my + qw * ty + (qz * tx - qx * tz) + np7[1];
            rm[s * 3 + 2] = mz + qw * tz + (qx * ty - qy * tx) + np7[2];
        }
        if (tid < NF) {
            float v;
            if (tid < 7) v = np7[tid];
            else {
                int j = tid - 7;
                int fi = j / 14, r = j % 14;
                float band = (float)(1 << fi);
                v = (r < 7) ? sinf(np7[r] * band) : cosf(np7[r - 7] * band);
            }
            nb[s * NF + tid] = v;
        }
    } else if (blk < 768) {
        int q = blk - SSEG;
        int b = q >> 2, jq = q & 3;
        float* e = sh;             // [512]
        float* red = sh + 512;     // [2][128]
        float tf = (float)tsteps[b];
        float f = expf(-9.210340371976184f * (float)tid * (1.f / 256.f));
        float sn, cs;
        sincosf(tf * f, &sn, &cs);
        e[tid] = cs;
        e[tid + 256] = sn;
        __syncthreads();
        int jj = tid & 127, j = jq * 128 + jj;
        int ks = tid >> 7, k0 = ks << 8;
        float acc = 0.f;
        #pragma unroll 8
        for (int k = k0; k < k0 + 256; k++) acc += e[k] * t_w1[k * 512 + j];
        red[ks * 128 + jj] = acc;
        __syncthreads();
        if (tid < 128) {
            float v = red[tid] + red[128 + tid] + t_b1[jq * 128 + tid];
            h1[b * 512 + jq * 128 + tid] = v / (1.f + expf(-v));
        }
    } else if (blk < 896) {
        int m = blk - 768;
        int kr = m * 4 + (tid >> 6);
        int c4 = (tid & 63) << 2;
        const float* t2row = t_w2 + (size_t)kr * 512;
        float4 acc = {0.f, 0.f, 0.f, 0.f};
        #pragma unroll 4
        for (int j = 0; j < 512; j++) {
            float4 w = *(const float4*)&o_w1[j * 256 + c4];
            float t2 = t2row[j];
            acc.x += t2 * w.x; acc.y += t2 * w.y; acc.z += t2 * w.z; acc.w += t2 * w.w;
        }
        *(float4*)&Mm[kr * 256 + c4] = acc;
    } else if (blk < 898) {
        int ch = blk - 896;
        int cc = tid & 127, c = ch * 128 + cc;
        int ks = tid >> 7, k0 = ks << 8;
        float acc = 0.f;
        #pragma unroll 8
        for (int j = k0; j < k0 + 256; j++) acc += t_b2[j] * o_w1[j * 256 + c];
        sh[tid] = acc;
        __syncthreads();
        if (tid < 128) cv[c] = sh[tid] + sh[128 + tid] + o_b1[c];
    } else {
        for (int z = tid; z < 772; z += 256) statsz[z] = 0;
    }
}

// ---------------------------------------------------------------------------
// kB (704 blocks x 256):
//   0..639    segment s: pool-base row (512, no temb) in LDS, fc1 -> g1[s][256]
//             (direct coalesced o_w1 column reads; L2 warmed by kA)
//   640..703  tg[b][c-half] = h1[b,:] @ M[:,c] + cv[c]   (k-split 2)
// ---------------------------------------------------------------------------
__global__ __launch_bounds__(256) void kB(
    const float* __restrict__ rm, const float* __restrict__ nb,
    const float* __restrict__ h1, const float* __restrict__ Mm,
    const float* __restrict__ cv,
    const float* __restrict__ pe_w, const float* __restrict__ pe_b,
    const float* __restrict__ pfc_w, const float* __restrict__ pfc_b,
    const float* __restrict__ o_w1,
    float* __restrict__ g1, float* __restrict__ tg)
{
    __shared__ float sh[768];
    int blk = blockIdx.x, tid = threadIdx.x;

    if (blk < SSEG) {
        int s = blk;
        float* pool = sh;          // [512]
        float* nbs = sh + 512;     // [147]
        if (tid < NF) nbs[tid] = nb[s * NF + tid];
        __shared__ float rms[3];
        if (tid < 3) rms[tid] = rm[s * 3 + tid];
        __syncthreads();
        #pragma unroll
        for (int h = 0; h < 2; h++) {
            int j = h * 256 + tid;
            float acc = pfc_b[j] + pe_b[j];
            acc += rms[0] * pe_w[j] + rms[1] * pe_w[512 + j] + rms[2] * pe_w[1024 + j];
            #pragma unroll 7
            for (int k = 0; k < NF; k++) acc += nbs[k] * pfc_w[k * 512 + j];
            pool[j] = acc;
        }
        __syncthreads();
        float acc = 0.f;
        #pragma unroll 8
        for (int k = 0; k < 512; k++) acc += pool[k] * o_w1[k * 256 + tid];
        g1[s * 256 + tid] = acc;
    } else {
        int q = blk - SSEG;
        int b = q >> 1, ch = q & 1;
        float* hrow = sh;          // [512]
        float* red = sh + 512;     // [2][128]
        hrow[tid] = h1[b * 512 + tid];
        hrow[tid + 256] = h1[b * 512 + 256 + tid];
        __syncthreads();
        int cc = tid & 127, c = ch * 128 + cc;
        int ks = tid >> 7, k0 = ks << 8;
        float acc = 0.f;
        #pragma unroll 8
        for (int k = k0; k < k0 + 256; k++) acc += hrow[k] * Mm[k * 256 + c];
        red[ks * 128 + cc] = acc;
        __syncthreads();
        if (tid < 128) tg[b * 256 + ch * 128 + tid] = red[tid] + red[128 + tid] + cv[ch * 128 + tid];
    }
}

// ---------------------------------------------------------------------------
// kCD: 80 blocks x 128 threads, co-resident.
//   phase0: rows = g1 + tg ; local col sums -> stats1 atomics
//   barrier1 ; bn1+relu ; fc2 -> acc[8] ; stats2 atomics ; barrier2
//   bn2+relu ; fc3 -> out(640,7)
// ---------------------------------------------------------------------------
__global__ __launch_bounds__(128) void kCD(
    const float* __restrict__ g1, const float* __restrict__ tg,
    float* __restrict__ stats1,
    const float* __restrict__ bn1_g, const float* __restrict__ bn1_b,
    const float* __restrict__ o_w2, const float* __restrict__ o_b2,
    const float* __restrict__ bn2_g, const float* __restrict__ bn2_b,
    const float* __restrict__ o_w3, const float* __restrict__ o_b3,
    float* __restrict__ stats2, int* __restrict__ cntA, int* __restrict__ cntB,
    float* __restrict__ out)
{
    int blk = blockIdx.x, tid = threadIdx.x;
    int r0 = blk * 8;
    __shared__ float rows[8][256];
    __shared__ float scale[256], shift[256];
    __shared__ float rowsB[8][128];
    __shared__ float w3[128 * 7];

    #pragma unroll
    for (int w = 0; w < 4; w++) {
        int idx4 = (tid + w * 128) << 2;           // 0..2044 step 4
        int r = idx4 >> 8, c = idx4 & 255;
        int s = r0 + r;
        float4 gv = *(const float4*)&g1[s * 256 + c];
        float4 tv = *(const float4*)&tg[(s / 20) * 256 + c];
        gv.x += tv.x; gv.y += tv.y; gv.z += tv.z; gv.w += tv.w;
        *(float4*)&rows[r][c] = gv;
    }
    for (int i = tid; i < 128 * 7; i += 128) w3[i] = o_w3[i];
    __syncthreads();
    for (int c = tid; c < 256; c += 128) {
        float sm = 0.f, ss = 0.f;
        #pragma unroll
        for (int r = 0; r < 8; r++) { float x = rows[r][c]; sm += x; ss += x * x; }
        atomicAdd(&stats1[c], sm);
        atomicAdd(&stats1[256 + c], ss);
    }

    __syncthreads();
    if (tid == 0) {
        __threadfence();
        atomicAdd(cntA, 1);
        while (atomicAdd(cntA, 0) < 80) { }
        __threadfence();
    }
    __syncthreads();

    for (int c = tid; c < 256; c += 128) {
        float m = stats1[c] * (1.f / 640.f);
        float v = stats1[256 + c] * (1.f / 640.f) - m * m;
        float sc = rsqrtf(v + 1e-5f) * bn1_g[c];
        scale[c] = sc;
        shift[c] = bn1_b[c] - m * sc;
    }
    __syncthreads();
    for (int i = tid; i < 2048; i += 128) {
        int r = i >> 8, c = i & 255;
        float x = rows[r][c] * scale[c] + shift[c];
        rows[r][c] = x > 0.f ? x : 0.f;
    }
    __syncthreads();

    float acc[8];
    float bb = o_b2[tid];
    #pragma unroll
    for (int r = 0; r < 8; r++) acc[r] = bb;
    #pragma unroll 8
    for (int k = 0; k < 256; k++) {
        float w = o_w2[k * 128 + tid];
        #pragma unroll
        for (int r = 0; r < 8; r++) acc[r] += rows[r][k] * w;
    }
    float sm = 0.f, ss = 0.f;
    #pragma unroll
    for (int r = 0; r < 8; r++) { sm += acc[r]; ss += acc[r] * acc[r]; }
    atomicAdd(&stats2[tid], sm);
    atomicAdd(&stats2[128 + tid], ss);

    __syncthreads();
    if (tid == 0) {
        __threadfence();
        atomicAdd(cntB, 1);
        while (atomicAdd(cntB, 0) < 80) { }
        __threadfence();
    }
    __syncthreads();

    {
        float m = stats2[tid] * (1.f / 640.f);
        float v = stats2[128 + tid] * (1.f / 640.f) - m * m;
        float sc = rsqrtf(v + 1e-5f) * bn2_g[tid];
        float sh2 = bn2_b[tid] - m * sc;
        #pragma unroll
        for (int r = 0; r < 8; r++) {
            float x = acc[r] * sc + sh2;
            rowsB[r][tid] = x > 0.f ? x : 0.f;
        }
    }
    __syncthreads();
    if (tid < 56) {
        int r = tid / 7, j = tid % 7;
        float a3 = o_b3[j];
        #pragma unroll 8
        for (int k = 0; k < 128; k++) a3 += rowsB[r][k] * w3[k * 7 + j];
        out[(r0 + r) * 7 + j] = a3;
    }
}

extern "C" void kernel_launch(void* const* d_in, const int* in_sizes, int n_in,
                              void* d_out, int out_size, void* d_ws, size_t ws_size,
                              hipStream_t stream) {
    const float* noise = (const float*)d_in[0];
    const int* tsteps = (const int*)d_in[1];
    const float* pcs = (const float*)d_in[2];
    const int* bl = (const int*)d_in[4];
    const float* pe_w = (const float*)d_in[5];
    const float* pe_b = (const float*)d_in[6];
    const float* t_w1 = (const float*)d_in[7];
    const float* t_b1 = (const float*)d_in[8];
    const float* t_w2 = (const float*)d_in[9];
    const float* t_b2 = (const float*)d_in[10];
    const float* pfc_w = (const float*)d_in[11];
    const float* pfc_b = (const float*)d_in[12];
    const float* o_w1 = (const float*)d_in[13];
    const float* o_b1 = (const float*)d_in[14];
    const float* bn1_g = (const float*)d_in[15];
    const float* bn1_b = (const float*)d_in[16];
    const float* o_w2 = (const float*)d_in[17];
    const float* o_b2 = (const float*)d_in[18];
    const float* bn2_g = (const float*)d_in[19];
    const float* bn2_b = (const float*)d_in[20];
    const float* o_w3 = (const float*)d_in[21];
    const float* o_b3 = (const float*)d_in[22];

    float* ws = (float*)d_ws;
    float* rm    = ws + 0;        // 1920
    float* nb    = ws + 1920;     // -> 96000
    float* h1    = ws + 96000;    // 32*512  -> 112384
    float* Mm    = ws + 112384;   // 512*256 -> 243456
    float* cv    = ws + 243456;   // 256     -> 243712
    float* g1    = ws + 243712;   // 640*256 -> 407552
    float* tg    = ws + 407552;   // 32*256  -> 415744
    float* stats = ws + 415744;   // 768
    int*   cnt   = (int*)(ws + 416512); // 2 counters

    kA<<<899, 256, 0, stream>>>(noise, pcs, bl, tsteps, t_w1, t_b1, t_w2, t_b2,
                                o_w1, o_b1, rm, nb, h1, Mm, cv, (int*)stats);
    kB<<<704, 256, 0, stream>>>(rm, nb, h1, Mm, cv, pe_w, pe_b, pfc_w, pfc_b,
                                o_w1, g1, tg);
    kCD<<<80, 128, 0, stream>>>(g1, tg, stats, bn1_g, bn1_b, o_w2, o_b2,
                                bn2_g, bn2_b, o_w3, o_b3,
                                stats + 512, cnt, cnt + 1, (float*)d_out);
}